// Round 7
// baseline (213.130 us; speedup 1.0000x reference)
//
#include <hip/hip_runtime.h>
#include <math.h>

#define NB 1024
#define NF 36
#define ED 256
#define NK 8
#define NN2 1296   // 36*36
#define QPK 162    // 1296/8

typedef _Float16 f16;
typedef f16 f16x8 __attribute__((ext_vector_type(8)));
typedef float f32x4 __attribute__((ext_vector_type(4)));

#define WXSTR 136     // f16 per Wx half-row (128 + 8 pad); 272B = 17*16 (b128-aligned)
#define WXHSZ 13056   // 48 * WXSTR * 2 bytes (one k)
#define WXF   6528    // f16 elements per k's Wxh
#define NFRAG 1536    // 3 row-tiles * 8 kc * 64 lanes, f16x8 each

// ---- ntn_main LDS: Xh | Wxh[2]/Ts | v1 v2 Uw L = 52596 B -> 3 blocks/CU ----
#define XH_OFF  0
#define WXH_OFF 24576
#define V_OFF   (24576 + 2 * WXHSZ)              // 50688
#define SMEM_MAIN (V_OFF + (72 + 72 + 9 + 324) * 4)   // 52596; 3x = 157788 <= 163840

// ---- prep_all LDS: VfH | VfL | partials  = 28672 B -> 5 blocks/CU ----
#define PVH_OFF 0
#define PVL_OFF 8192
#define PP_OFF  16384
#define SMEM_PREP 28672

#define TWO_LOG2E 2.8853900817779268f
#define C1F (0.0625f * TWO_LOG2E)

__device__ __forceinline__ f32x4 mfma16(f16x8 a, f16x8 b, f32x4 c) {
    return __builtin_amdgcn_mfma_f32_16x16x32_f16(a, b, c, 0, 0, 0);
}

// blocks [0,128): W fragment pack, one (k,ct) tile per block.
// blocks [128,1152): X fragment pack (register-resident) + v12 via per-wave
//   kc-partial MFMAs + LDS reduction.
// Wb is folded into the v2 row: v2'[k,m] = (V2w[k]+Wb[k]).x_m + V2b[k].
__global__ __launch_bounds__(256, 4) void prep_all(
    const float* __restrict__ W, f16x8* __restrict__ WfH,
    const float* __restrict__ texts, f16x8* __restrict__ XfH, f16x8* __restrict__ XfL,
    const float* __restrict__ V1w, const float* __restrict__ V1b,
    const float* __restrict__ V2w, const float* __restrict__ V2b,
    const float* __restrict__ Wb, float* __restrict__ v12)
{
    extern __shared__ char psmem[];
    const int blk = blockIdx.x;
    const int t = threadIdx.x;
    const int wave = t >> 6, lane = t & 63;

    if (blk < 128) {   // ---- W pack: (k, ct) tile ----
        const int k = blk >> 4, ct = blk & 15;
        f16* Wl = (f16*)psmem;                    // [16][264] f16, scaled x16
        {
            const int r = t >> 4, seg = t & 15;   // row in tile, 16-float segment
            const float* src = W + ((size_t)(k * 256 + ct * 16 + r)) * 256 + seg * 16;
            f16* d = Wl + r * 264 + seg * 16;
            #pragma unroll
            for (int j4 = 0; j4 < 4; ++j4) {
                float4 a = ((const float4*)src)[j4];
                d[j4 * 4 + 0] = (f16)(a.x * 16.0f);
                d[j4 * 4 + 1] = (f16)(a.y * 16.0f);
                d[j4 * 4 + 2] = (f16)(a.z * 16.0f);
                d[j4 * 4 + 3] = (f16)(a.w * 16.0f);
            }
        }
        __syncthreads();
        f16x8* dst = WfH + (size_t)(k * 16 + ct) * 8 * 64;
        #pragma unroll
        for (int e0 = 0; e0 < 2; ++e0) {
            const int e = t + e0 * 256;           // [0,512) output entries
            const int kc = e >> 6, el = e & 63, qd = el >> 4, l15 = el & 15;
            dst[e] = *(const f16x8*)(Wl + l15 * 264 + (kc * 4 + qd) * 8);
        }
        return;
    }

    // ---- X fragment pack + v12 ----
    f16x8* VfH = (f16x8*)(psmem + PVH_OFF);
    f16x8* VfL = (f16x8*)(psmem + PVL_OFF);
    f32x4* Pp  = (f32x4*)(psmem + PP_OFF);        // [4 waves][3 rt][64 lanes]

    const int b = blk - 128;
    const float* xb = texts + (size_t)b * NF * ED;

    // V fragments: col = which*8 + k at lane&15; scaled by 16; Wb folded into V2
    #pragma unroll
    for (int i0 = 0; i0 < 2; ++i0) {
        int i = t + i0 * 256;          // [0,512)
        int kc = (i >> 6) & 7, ln = i & 63;
        int q = ln >> 4, col = ln & 15;
        int which = col >> 3, kk = col & 7;
        const float* src  = (which ? V2w : V1w) + kk * 256 + kc * 32 + q * 8;
        const float* srcb = Wb + kk * 256 + kc * 32 + q * 8;
        f16x8 hi, lo;
        #pragma unroll
        for (int j = 0; j < 8; ++j) {
            float sv = src[j] + (which ? srcb[j] : 0.f);
            sv *= 16.0f;
            f16 h = (f16)sv;
            hi[j] = h;
            lo[j] = (f16)(sv - (float)h);
        }
        VfH[i] = hi;
        VfL[i] = lo;
    }

    // X fragments: direct global gather -> registers + global store.
    f16x8 FH[6], FL[6];
    #pragma unroll
    for (int i0 = 0; i0 < 6; ++i0) {
        int i = t + i0 * 256;          // [0,1536)
        int rt = i >> 9, kc = (i >> 6) & 7;
        int q = lane >> 4, l15 = lane & 15;
        int row = rt * 16 + l15;
        f16x8 hi, lo;
        if (row < NF) {
            const float* s = xb + row * ED + kc * 32 + q * 8;
            float4 a = *(const float4*)s;
            float4 c = *(const float4*)(s + 4);
            float v[8] = {a.x, a.y, a.z, a.w, c.x, c.y, c.z, c.w};
            #pragma unroll
            for (int j = 0; j < 8; ++j) {
                f16 h = (f16)v[j];
                hi[j] = h;
                lo[j] = (f16)(v[j] - (float)h);
            }
        } else {
            #pragma unroll
            for (int j = 0; j < 8; ++j) { hi[j] = (f16)0.f; lo[j] = (f16)0.f; }
        }
        FH[i0] = hi;
        FL[i0] = lo;
        XfH[(size_t)b * NFRAG + i] = hi;
        XfL[(size_t)b * NFRAG + i] = lo;
    }
    __syncthreads();   // VfH/VfL staged

    // per-wave kc-partials of v12 (kc = wave and wave+4), all 3 row-tiles
    f32x4 pacc[3];
    #pragma unroll
    for (int rt = 0; rt < 3; ++rt) pacc[rt] = (f32x4){0.f, 0.f, 0.f, 0.f};
    #pragma unroll
    for (int rt = 0; rt < 3; ++rt) {
        #pragma unroll
        for (int s = 0; s < 2; ++s) {
            const int i0 = rt * 2 + s;          // frag (rt, kc = wave + 4*s)
            const int kc = wave + 4 * s;
            f16x8 bh = VfH[kc * 64 + lane];
            f16x8 bl = VfL[kc * 64 + lane];
            pacc[rt] = mfma16(FH[i0], bh, pacc[rt]);
            pacc[rt] = mfma16(FH[i0], bl, pacc[rt]);
            pacc[rt] = mfma16(FL[i0], bh, pacc[rt]);
        }
    }
    #pragma unroll
    for (int rt = 0; rt < 3; ++rt)
        Pp[(wave * 3 + rt) * 64 + lane] = pacc[rt];
    __syncthreads();

    // reduce 4 wave-partials; wave rt (<3) owns row-tile rt
    if (wave < 3) {
        f32x4 acc = Pp[(0 * 3 + wave) * 64 + lane];
        #pragma unroll
        for (int w = 1; w < 4; ++w) acc += Pp[(w * 3 + wave) * 64 + lane];
        const int q = lane >> 4, l15 = lane & 15;
        const int which = l15 >> 3, kk = l15 & 7;
        const float bias = which ? V2b[kk] : V1b[kk];
        #pragma unroll
        for (int r = 0; r < 4; ++r) {
            const int n = wave * 16 + q * 4 + r;
            if (n < NF)
                v12[((size_t)b * 16 + l15) * NF + n] = acc[r] * 0.0625f + bias;
        }
    }
}

// phase-2 tile: p = wave + IT*4 in [0,18): kk = p/9, (nt,mt) from p%9.
// Reads Wxh[kk] (h-half H contents) and Xh/Xlg; accumulates sacc[IT].
#define P2_TILE(IT, H) do {                                                   \
    const int p_ = wave + (IT) * 4;                                           \
    if (p_ < 18) {                                                            \
        const int kkp_ = p_ / 9, q9_ = p_ - kkp_ * 9;                         \
        const int nt_ = q9_ / 3, mt_ = q9_ - nt_ * 3;                         \
        const f16* wp_ = Wxh + kkp_ * WXF + (nt_ * 16 + l15) * WXSTR + quad * 8; \
        _Pragma("unroll")                                                     \
        for (int kc2 = 0; kc2 < 4; ++kc2) {                                   \
            f16x8 pah = *(const f16x8*)(wp_ + kc2 * 32);                      \
            f16x8 pbh = Xh[(mt_ * 8 + (H) * 4 + kc2) * 64 + lane];            \
            f16x8 pbl = Xlg[(mt_ * 8 + (H) * 4 + kc2) * 64 + lane];           \
            sacc[IT] = mfma16(pah, pbh, sacc[IT]);                            \
            sacc[IT] = mfma16(pah, pbl, sacc[IT]);                            \
        }                                                                     \
    }                                                                         \
} while (0)

// k-pair merged main, double-Wxh (one per k) + h-pipelined:
//   phase1(h0) -> store both Wx(h0) -> [phase2(h0) 18 tiles || phase1(h1)]
//   -> store both Wx(h1) -> phase2(h1) -> fused tanh/U-dot/softmax.
// 7 barriers/block (was 12); phase-2 tiles balanced 5/5/4/4 per wave.
// Phase 1 is Xh-only (validated R6); phase 2 keeps Xh+Xl.
// Wxh stays *16-scaled (exact in f16); 0.0625*2*log2e folded into epilogue fma.
__global__ __launch_bounds__(256, 3) void ntn_main(
    const f16x8* __restrict__ XfHG, const f16x8* __restrict__ XfLG,
    const f16x8* __restrict__ WfH,
    const float* __restrict__ v12,
    const float* __restrict__ Uw, const float* __restrict__ Ubp,
    float* __restrict__ out)
{
    extern __shared__ char smem[];
    f16x8* Xh   = (f16x8*)(smem + XH_OFF);
    f16*   Wxh  = (f16*)(smem + WXH_OFF);      // [2][48][WXSTR]
    float* v1s2 = (float*)(smem + V_OFF);      // [2][36], pre-scaled by 2*log2e
    float* v2s2 = v1s2 + 72;                   // [2][36]
    float* Uws  = v1s2 + 144;                  // [9]
    float* Ls   = v1s2 + 153;                  // [324] logits

    // XCD swizzle: the 4 k-pair blocks of a given b share id&7 (same XCD)
    const int id  = blockIdx.x;
    const int xcd = id & 7;
    const int rem = id >> 3;
    const int kp  = rem & 3;
    const int b   = ((rem >> 2) << 3) | xcd;
    const int k0  = kp * 2;

    const int t    = threadIdx.x;
    const int wave = t >> 6;
    const int lane = t & 63;
    const int quad = lane >> 4;
    const int l15  = lane & 15;

    const f16x8* Xlg = XfLG + (size_t)b * NFRAG;   // X-lo: global (L2/L1)

    // ---- stage X-hi fragments into LDS (coalesced dwordx4) ----
    {
        const f16x8* gh = XfHG + (size_t)b * NFRAG;
        #pragma unroll
        for (int i = 0; i < 6; ++i) Xh[t + i * 256] = gh[t + i * 256];
    }
    if (t < 144) {
        const int r = t / 36, n = t - r * 36;
        const int which = r & 1, kq = r >> 1;
        float v = v12[((size_t)b * 16 + which * 8 + (k0 + kq)) * NF + n] * TWO_LOG2E;
        (which ? v2s2 : v1s2)[kq * 36 + n] = v;
    }
    if (t < 8) Uws[t] = Uw[t];
    if (t == 8) Uws[8] = Ubp[0];
    __syncthreads();   // (1)

    const f16x8* Wk0 = WfH + (size_t)k0 * 8192;   // 16ct*8kc*64
    const f16x8* Wk1 = Wk0 + 8192;

    f32x4 sacc[5];
    #pragma unroll
    for (int it = 0; it < 5; ++it) sacc[it] = (f32x4){0.f, 0.f, 0.f, 0.f};

    f32x4 acc[3][2][2];   // [rt][ctslot][kk]

    // ===== phase 1, h=0 (Xh-only) =====
    #pragma unroll
    for (int i = 0; i < 3; ++i)
        #pragma unroll
        for (int j = 0; j < 2; ++j) {
            acc[i][j][0] = (f32x4){0.f, 0.f, 0.f, 0.f};
            acc[i][j][1] = (f32x4){0.f, 0.f, 0.f, 0.f};
        }
    {
        const int ct0 = wave, ct1 = wave + 4;
        #pragma unroll 2
        for (int kc = 0; kc < 8; ++kc) {
            f16x8 w00 = Wk0[(ct0 * 8 + kc) * 64 + lane];
            f16x8 w01 = Wk0[(ct1 * 8 + kc) * 64 + lane];
            f16x8 w10 = Wk1[(ct0 * 8 + kc) * 64 + lane];
            f16x8 w11 = Wk1[(ct1 * 8 + kc) * 64 + lane];
            #pragma unroll
            for (int rt = 0; rt < 3; ++rt) {
                f16x8 ah = Xh[(rt * 8 + kc) * 64 + lane];
                acc[rt][0][0] = mfma16(ah, w00, acc[rt][0][0]);
                acc[rt][1][0] = mfma16(ah, w01, acc[rt][1][0]);
                acc[rt][0][1] = mfma16(ah, w10, acc[rt][0][1]);
                acc[rt][1][1] = mfma16(ah, w11, acc[rt][1][1]);
            }
        }
    }
    // store Wx(h0) for both k (Wxh unread so far: no barrier needed before)
    #pragma unroll
    for (int kk = 0; kk < 2; ++kk)
        #pragma unroll
        for (int rt = 0; rt < 3; ++rt)
            #pragma unroll
            for (int j2 = 0; j2 < 2; ++j2) {
                const int cl = (j2 ? (wave + 4) : wave) * 16 + l15;
                #pragma unroll
                for (int r = 0; r < 4; ++r) {
                    const int row = rt * 16 + quad * 4 + r;
                    Wxh[kk * WXF + row * WXSTR + cl] = (f16)(acc[rt][j2][kk][r]);
                }
            }
    __syncthreads();   // (2) Wx(h0) visible

    // ===== fat region: phase2(h0) tiles interleaved with phase1(h1) =====
    #pragma unroll
    for (int i = 0; i < 3; ++i)
        #pragma unroll
        for (int j = 0; j < 2; ++j) {
            acc[i][j][0] = (f32x4){0.f, 0.f, 0.f, 0.f};
            acc[i][j][1] = (f32x4){0.f, 0.f, 0.f, 0.f};
        }
    {
        const int ct0 = 8 + wave, ct1 = 12 + wave;
        #pragma unroll
        for (int step = 0; step < 8; ++step) {
            f16x8 w00 = Wk0[(ct0 * 8 + step) * 64 + lane];
            f16x8 w01 = Wk0[(ct1 * 8 + step) * 64 + lane];
            f16x8 w10 = Wk1[(ct0 * 8 + step) * 64 + lane];
            f16x8 w11 = Wk1[(ct1 * 8 + step) * 64 + lane];
            #pragma unroll
            for (int rt = 0; rt < 3; ++rt) {
                f16x8 ah = Xh[(rt * 8 + step) * 64 + lane];
                acc[rt][0][0] = mfma16(ah, w00, acc[rt][0][0]);
                acc[rt][1][0] = mfma16(ah, w01, acc[rt][1][0]);
                acc[rt][0][1] = mfma16(ah, w10, acc[rt][0][1]);
                acc[rt][1][1] = mfma16(ah, w11, acc[rt][1][1]);
            }
            if (step < 5) P2_TILE(step, 0);
        }
    }
    __syncthreads();   // (3) all phase2(h0) Wxh reads done

    // store Wx(h1) for both k
    #pragma unroll
    for (int kk = 0; kk < 2; ++kk)
        #pragma unroll
        for (int rt = 0; rt < 3; ++rt)
            #pragma unroll
            for (int j2 = 0; j2 < 2; ++j2) {
                const int cl = (j2 ? (wave + 4) : wave) * 16 + l15;
                #pragma unroll
                for (int r = 0; r < 4; ++r) {
                    const int row = rt * 16 + quad * 4 + r;
                    Wxh[kk * WXF + row * WXSTR + cl] = (f16)(acc[rt][j2][kk][r]);
                }
            }
    __syncthreads();   // (4) Wx(h1) visible

    // ===== phase2(h1) =====
    P2_TILE(0, 1);
    P2_TILE(1, 1);
    P2_TILE(2, 1);
    P2_TILE(3, 1);
    P2_TILE(4, 1);
    __syncthreads();   // (5) Wxh reads done before Ts overlay

    // ===== epilogue: T = tanh(S + v1 + v2) -> Ts (chunk-padded overlay) =====
    float* Ts = (float*)Wxh;   // padded: addr = idx + (idx>>3); max 2914 f32
    #pragma unroll
    for (int it = 0; it < 5; ++it) {
        const int p = wave + it * 4;
        if (p < 18) {
            const int kkp = p / 9, q9 = p - kkp * 9;
            const int nt = q9 / 3, mt = q9 - nt * 3;
            const int m = mt * 16 + l15;
            if (m < NF) {
                #pragma unroll
                for (int r = 0; r < 4; ++r) {
                    const int n = nt * 16 + quad * 4 + r;
                    if (n < NF) {
                        // x = 2*log2e * (S + v1 + v2); S = sacc * 0.0625
                        float x = sacc[it][r] * C1F
                                  + v1s2[kkp * 36 + n] + v2s2[kkp * 36 + m];
                        float e = exp2f(x);
                        const int idx = kkp * NN2 + n * NF + m;
                        Ts[idx + (idx >> 3)] = 1.f - 2.f / (e + 1.f);
                    }
                }
            }
        }
    }
    __syncthreads();   // (6)
    // U-dot: logit u consumes T_flat[u*8 .. u*8+7] = Ts[9u .. 9u+7]
    #pragma unroll
    for (int u0 = 0; u0 < 2; ++u0) {
        const int u = t + u0 * 256;
        if (u < 324) {
            const float* tp = Ts + u * 9;
            float lg = Uws[8];
            #pragma unroll
            for (int j = 0; j < 8; ++j) lg += Uws[j] * tp[j];
            Ls[u] = lg;
        }
    }
    __syncthreads();   // (7)
    // fused softmax: this block's 324 logits = rows [kp*9, kp*9+9) of out[b]
    #pragma unroll
    for (int rr0 = 0; rr0 < 3; ++rr0) {
        const int rr = wave + rr0 * 4;
        if (rr < 9) {
            float v = (lane < NF) ? Ls[rr * 36 + lane] : -INFINITY;
            float mx = v;
            #pragma unroll
            for (int off = 32; off > 0; off >>= 1) mx = fmaxf(mx, __shfl_xor(mx, off));
            float e = (lane < NF) ? __expf(v - mx) : 0.f;
            float sm = e;
            #pragma unroll
            for (int off = 32; off > 0; off >>= 1) sm += __shfl_xor(sm, off);
            if (lane < NF)
                out[(size_t)b * NN2 + kp * 324 + rr * 36 + lane] = e / sm;
        }
    }
}

extern "C" void kernel_launch(void* const* d_in, const int* in_sizes, int n_in,
                              void* d_out, int out_size, void* d_ws, size_t ws_size,
                              hipStream_t stream) {
    const float* texts = (const float*)d_in[0];
    const float* W     = (const float*)d_in[1];
    const float* Wb    = (const float*)d_in[2];
    const float* V1w   = (const float*)d_in[3];
    const float* V1b   = (const float*)d_in[4];
    const float* V2w   = (const float*)d_in[5];
    const float* V2b   = (const float*)d_in[6];
    const float* Uw    = (const float*)d_in[7];
    const float* Ub    = (const float*)d_in[8];

    char* ws = (char*)d_ws;
    f16x8* WfH = (f16x8*)ws;                                   //  1 MiB
    f16x8* XfH = (f16x8*)(ws + (1 << 20));                     // 24 MiB
    f16x8* XfL = (f16x8*)(ws + (1 << 20) + (size_t)NB * NFRAG * 16);       // 24 MiB
    float* v12 = (float*)(ws + (1 << 20) + (size_t)2 * NB * NFRAG * 16);   // 2.25 MiB
    float* outp = (float*)d_out;

    hipFuncSetAttribute((const void*)prep_all,
                        hipFuncAttributeMaxDynamicSharedMemorySize, SMEM_PREP);
    hipFuncSetAttribute((const void*)ntn_main,
                        hipFuncAttributeMaxDynamicSharedMemorySize, SMEM_MAIN);

    prep_all<<<128 + NB, 256, SMEM_PREP, stream>>>(W, WfH, texts, XfH, XfL,
                                                   V1w, V1b, V2w, V2b, Wb, v12);
    ntn_main<<<NB * NK / 2, 256, SMEM_MAIN, stream>>>(XfH, XfL, WfH, v12, Uw, Ub, outp);
}

// Round 8
// 199.524 us; speedup vs baseline: 1.0682x; 1.0682x over previous
//
#include <hip/hip_runtime.h>
#include <math.h>

#define NB 1024
#define NF 36
#define ED 256
#define NK 8
#define NN2 1296   // 36*36
#define QPK 162    // 1296/8

typedef _Float16 f16;
typedef f16 f16x4 __attribute__((ext_vector_type(4)));
typedef f16 f16x8 __attribute__((ext_vector_type(8)));
typedef float f32x4 __attribute__((ext_vector_type(4)));

#define WXSTR 136     // f16 per Wx half-row (128 + 8 pad); 272B = 17*16 (b128-aligned)
#define WXHSZ 13056   // 48 * WXSTR * 2 bytes
#define NFRAG 1536    // 3 row-tiles * 8 kc * 64 lanes, f16x8 each

// ---- ntn_main LDS: Xh | Wxh/Ts | v1 v2 Uw L  = 39540 B -> 4 blocks/CU ----
#define XH_OFF  0
#define WXH_OFF 24576
#define V_OFF   (24576 + WXHSZ)                  // 37632
#define SMEM_MAIN (V_OFF + (72 + 72 + 9 + 324) * 4)   // 39540; 4x = 158160 <= 163840

// ---- prep_all LDS: VfH | VfL | partials  = 28672 B -> 5 blocks/CU ----
#define PVH_OFF 0
#define PVL_OFF 8192
#define PP_OFF  16384
#define SMEM_PREP 28672

#define TWO_LOG2E 2.8853900817779268f
#define C1F (0.0625f * TWO_LOG2E)

__device__ __forceinline__ f32x4 mfma16(f16x8 a, f16x8 b, f32x4 c) {
    return __builtin_amdgcn_mfma_f32_16x16x32_f16(a, b, c, 0, 0, 0);
}

// blocks [0,128): W fragment pack, one (k,ct) tile per block.
// blocks [128,1152): X fragment pack (register-resident) + v12 via per-wave
//   kc-partial MFMAs + LDS reduction.
// Wb is folded into the v2 row: v2'[k,m] = (V2w[k]+Wb[k]).x_m + V2b[k].
__global__ __launch_bounds__(256, 4) void prep_all(
    const float* __restrict__ W, f16x8* __restrict__ WfH,
    const float* __restrict__ texts, f16x8* __restrict__ XfH, f16x8* __restrict__ XfL,
    const float* __restrict__ V1w, const float* __restrict__ V1b,
    const float* __restrict__ V2w, const float* __restrict__ V2b,
    const float* __restrict__ Wb, float* __restrict__ v12)
{
    extern __shared__ char psmem[];
    const int blk = blockIdx.x;
    const int t = threadIdx.x;
    const int wave = t >> 6, lane = t & 63;

    if (blk < 128) {   // ---- W pack: (k, ct) tile ----
        const int k = blk >> 4, ct = blk & 15;
        f16* Wl = (f16*)psmem;                    // [16][264] f16, scaled x16
        {
            const int r = t >> 4, seg = t & 15;   // row in tile, 16-float segment
            const float* src = W + ((size_t)(k * 256 + ct * 16 + r)) * 256 + seg * 16;
            f16* d = Wl + r * 264 + seg * 16;
            #pragma unroll
            for (int j4 = 0; j4 < 4; ++j4) {
                float4 a = ((const float4*)src)[j4];
                d[j4 * 4 + 0] = (f16)(a.x * 16.0f);
                d[j4 * 4 + 1] = (f16)(a.y * 16.0f);
                d[j4 * 4 + 2] = (f16)(a.z * 16.0f);
                d[j4 * 4 + 3] = (f16)(a.w * 16.0f);
            }
        }
        __syncthreads();
        f16x8* dst = WfH + (size_t)(k * 16 + ct) * 8 * 64;
        #pragma unroll
        for (int e0 = 0; e0 < 2; ++e0) {
            const int e = t + e0 * 256;           // [0,512) output entries
            const int kc = e >> 6, el = e & 63, qd = el >> 4, l15 = el & 15;
            dst[e] = *(const f16x8*)(Wl + l15 * 264 + (kc * 4 + qd) * 8);
        }
        return;
    }

    // ---- X fragment pack + v12 ----
    f16x8* VfH = (f16x8*)(psmem + PVH_OFF);
    f16x8* VfL = (f16x8*)(psmem + PVL_OFF);
    f32x4* Pp  = (f32x4*)(psmem + PP_OFF);        // [4 waves][3 rt][64 lanes]

    const int b = blk - 128;
    const float* xb = texts + (size_t)b * NF * ED;

    // V fragments: col = which*8 + k at lane&15; scaled by 16; Wb folded into V2
    #pragma unroll
    for (int i0 = 0; i0 < 2; ++i0) {
        int i = t + i0 * 256;          // [0,512)
        int kc = (i >> 6) & 7, ln = i & 63;
        int q = ln >> 4, col = ln & 15;
        int which = col >> 3, kk = col & 7;
        const float* src  = (which ? V2w : V1w) + kk * 256 + kc * 32 + q * 8;
        const float* srcb = Wb + kk * 256 + kc * 32 + q * 8;
        f16x8 hi, lo;
        #pragma unroll
        for (int j = 0; j < 8; ++j) {
            float sv = src[j] + (which ? srcb[j] : 0.f);
            sv *= 16.0f;
            f16 h = (f16)sv;
            hi[j] = h;
            lo[j] = (f16)(sv - (float)h);
        }
        VfH[i] = hi;
        VfL[i] = lo;
    }

    // X fragments: direct global gather -> registers + global store.
    f16x8 FH[6], FL[6];
    #pragma unroll
    for (int i0 = 0; i0 < 6; ++i0) {
        int i = t + i0 * 256;          // [0,1536)
        int rt = i >> 9, kc = (i >> 6) & 7;
        int q = lane >> 4, l15 = lane & 15;
        int row = rt * 16 + l15;
        f16x8 hi, lo;
        if (row < NF) {
            const float* s = xb + row * ED + kc * 32 + q * 8;
            float4 a = *(const float4*)s;
            float4 c = *(const float4*)(s + 4);
            float v[8] = {a.x, a.y, a.z, a.w, c.x, c.y, c.z, c.w};
            #pragma unroll
            for (int j = 0; j < 8; ++j) {
                f16 h = (f16)v[j];
                hi[j] = h;
                lo[j] = (f16)(v[j] - (float)h);
            }
        } else {
            #pragma unroll
            for (int j = 0; j < 8; ++j) { hi[j] = (f16)0.f; lo[j] = (f16)0.f; }
        }
        FH[i0] = hi;
        FL[i0] = lo;
        XfH[(size_t)b * NFRAG + i] = hi;
        XfL[(size_t)b * NFRAG + i] = lo;
    }
    __syncthreads();   // VfH/VfL staged

    // per-wave kc-partials of v12 (kc = wave and wave+4), all 3 row-tiles
    f32x4 pacc[3];
    #pragma unroll
    for (int rt = 0; rt < 3; ++rt) pacc[rt] = (f32x4){0.f, 0.f, 0.f, 0.f};
    #pragma unroll
    for (int rt = 0; rt < 3; ++rt) {
        #pragma unroll
        for (int s = 0; s < 2; ++s) {
            const int i0 = rt * 2 + s;          // frag (rt, kc = wave + 4*s)
            const int kc = wave + 4 * s;
            f16x8 bh = VfH[kc * 64 + lane];
            f16x8 bl = VfL[kc * 64 + lane];
            pacc[rt] = mfma16(FH[i0], bh, pacc[rt]);
            pacc[rt] = mfma16(FH[i0], bl, pacc[rt]);
            pacc[rt] = mfma16(FL[i0], bh, pacc[rt]);
        }
    }
    #pragma unroll
    for (int rt = 0; rt < 3; ++rt)
        Pp[(wave * 3 + rt) * 64 + lane] = pacc[rt];
    __syncthreads();

    // reduce 4 wave-partials; wave rt (<3) owns row-tile rt
    if (wave < 3) {
        f32x4 acc = Pp[(0 * 3 + wave) * 64 + lane];
        #pragma unroll
        for (int w = 1; w < 4; ++w) acc += Pp[(w * 3 + wave) * 64 + lane];
        const int q = lane >> 4, l15 = lane & 15;
        const int which = l15 >> 3, kk = l15 & 7;
        const float bias = which ? V2b[kk] : V1b[kk];
        #pragma unroll
        for (int r = 0; r < 4; ++r) {
            const int n = wave * 16 + q * 4 + r;
            if (n < NF)
                v12[((size_t)b * 16 + l15) * NF + n] = acc[r] * 0.0625f + bias;
        }
    }
}

// k-pair merged main (Xh staged in LDS, X-lo from global) + fused softmax.
// Phase 1: Wx = Xh * Wh only (validated R6), computed with SWAPPED MFMA
// operands -> D[c][n] transposed accumulator: lane holds 4 consecutive
// columns of one Wxh row, so the store is a packed f16x4 ds_write_b64
// (was 4 scalar cvt + 4 scalar ds_write_b16 per fragment row).
// A/B fragment layouts of 16x16x32_f16 are symmetric, so swap is exact.
// Phase 2 keeps Xh+Xl. Wxh stays *16-scaled; 0.0625*2*log2e folded into
// the epilogue fma.
__global__ __launch_bounds__(256, 4) void ntn_main(
    const f16x8* __restrict__ XfHG, const f16x8* __restrict__ XfLG,
    const f16x8* __restrict__ WfH,
    const float* __restrict__ v12,
    const float* __restrict__ Uw, const float* __restrict__ Ubp,
    float* __restrict__ out)
{
    extern __shared__ char smem[];
    f16x8* Xh   = (f16x8*)(smem + XH_OFF);
    f16*   Wxh  = (f16*)(smem + WXH_OFF);
    float* v1s2 = (float*)(smem + V_OFF);      // [2][36], pre-scaled by 2*log2e
    float* v2s2 = v1s2 + 72;                   // [2][36]
    float* Uws  = v1s2 + 144;                  // [9]
    float* Ls   = v1s2 + 153;                  // [324] logits

    // XCD swizzle: the 4 k-pair blocks of a given b share id&7 (same XCD)
    const int id  = blockIdx.x;
    const int xcd = id & 7;
    const int rem = id >> 3;
    const int kp  = rem & 3;
    const int b   = ((rem >> 2) << 3) | xcd;
    const int k0  = kp * 2;

    const int t    = threadIdx.x;
    const int wave = t >> 6;
    const int lane = t & 63;
    const int quad = lane >> 4;
    const int l15  = lane & 15;

    const f16x8* Xlg = XfLG + (size_t)b * NFRAG;   // X-lo: global (L2/L1)

    // ---- stage X-hi fragments into LDS (coalesced dwordx4) ----
    {
        const f16x8* gh = XfHG + (size_t)b * NFRAG;
        #pragma unroll
        for (int i = 0; i < 6; ++i) Xh[t + i * 256] = gh[t + i * 256];
    }
    if (t < 144) {
        const int r = t / 36, n = t - r * 36;
        const int which = r & 1, kq = r >> 1;
        float v = v12[((size_t)b * 16 + which * 8 + (k0 + kq)) * NF + n] * TWO_LOG2E;
        (which ? v2s2 : v1s2)[kq * 36 + n] = v;
    }
    if (t < 8) Uws[t] = Uw[t];
    if (t == 8) Uws[8] = Ubp[0];
    __syncthreads();

    const f16x8* Wk0 = WfH + (size_t)k0 * 8192;   // 16ct*8kc*64
    const f16x8* Wk1 = Wk0 + 8192;

    f32x4 sacc[2][3];
    #pragma unroll
    for (int kk = 0; kk < 2; ++kk)
        #pragma unroll
        for (int it = 0; it < 3; ++it) sacc[kk][it] = (f32x4){0.f, 0.f, 0.f, 0.f};

    for (int h = 0; h < 2; ++h) {
        // ===== phase 1: Wx^T[, half h] for BOTH k's; swapped operands =====
        // acc[rt][j2][kk][r] = Wx[n = rt*16 + l15][c = ct*16 + quad*4 + r]
        f32x4 acc[3][2][2];   // [rt][ctslot][kk]
        #pragma unroll
        for (int i = 0; i < 3; ++i)
            #pragma unroll
            for (int j = 0; j < 2; ++j) {
                acc[i][j][0] = (f32x4){0.f, 0.f, 0.f, 0.f};
                acc[i][j][1] = (f32x4){0.f, 0.f, 0.f, 0.f};
            }
        const int ct0 = h * 8 + wave;
        const int ct1 = ct0 + 4;
        #pragma unroll 2
        for (int kc = 0; kc < 8; ++kc) {
            f16x8 w00 = Wk0[(ct0 * 8 + kc) * 64 + lane];
            f16x8 w01 = Wk0[(ct1 * 8 + kc) * 64 + lane];
            f16x8 w10 = Wk1[(ct0 * 8 + kc) * 64 + lane];
            f16x8 w11 = Wk1[(ct1 * 8 + kc) * 64 + lane];
            #pragma unroll
            for (int rt = 0; rt < 3; ++rt) {
                f16x8 ah = Xh[(rt * 8 + kc) * 64 + lane];    // LDS ds_read_b128
                acc[rt][0][0] = mfma16(w00, ah, acc[rt][0][0]);
                acc[rt][1][0] = mfma16(w01, ah, acc[rt][1][0]);
                acc[rt][0][1] = mfma16(w10, ah, acc[rt][0][1]);
                acc[rt][1][1] = mfma16(w11, ah, acc[rt][1][1]);
            }
        }
        // ===== per-k sequential: packed f16x4 store -> phase 2 =====
        #pragma unroll
        for (int kk = 0; kk < 2; ++kk) {
            __syncthreads();   // previous Wxh readers done
            #pragma unroll
            for (int rt = 0; rt < 3; ++rt) {
                const int n = rt * 16 + l15;
                #pragma unroll
                for (int j2 = 0; j2 < 2; ++j2) {
                    const int cb = (j2 ? (wave + 4) : wave) * 16 + quad * 4;
                    f16x4 h4;
                    #pragma unroll
                    for (int r = 0; r < 4; ++r) h4[r] = (f16)(acc[rt][j2][kk][r]);
                    *(f16x4*)(Wxh + n * WXSTR + cb) = h4;   // ds_write_b64
                }
            }
            __syncthreads();
            // phase 2: S_kk += Wxh * (Xh + Xl)^T (9 tiles over 4 waves)
            #pragma unroll
            for (int it = 0; it < 3; ++it) {
                const int p = wave + it * 4;
                if (p < 9) {
                    const int nt = p / 3, mt = p % 3;
                    const f16* wxh_p = Wxh + (nt * 16 + l15) * WXSTR + quad * 8;
                    #pragma unroll
                    for (int kc2 = 0; kc2 < 4; ++kc2) {
                        f16x8 pah = *(const f16x8*)(wxh_p + kc2 * 32);
                        f16x8 pbh = Xh[(mt * 8 + h * 4 + kc2) * 64 + lane];
                        f16x8 pbl = Xlg[(mt * 8 + h * 4 + kc2) * 64 + lane];
                        sacc[kk][it] = mfma16(pah, pbh, sacc[kk][it]);
                        sacc[kk][it] = mfma16(pah, pbl, sacc[kk][it]);
                    }
                }
            }
        }
    }

    // ===== epilogue: T = tanh(S + v1 + v2) -> Ts (chunk-padded, overlays Wxh) =====
    __syncthreads();
    float* Ts = (float*)Wxh;   // padded: addr = idx + (idx>>3)
    #pragma unroll
    for (int kk = 0; kk < 2; ++kk)
        #pragma unroll
        for (int it = 0; it < 3; ++it) {
            const int p = wave + it * 4;
            if (p < 9) {
                const int nt = p / 3, mt = p % 3;
                const int m = mt * 16 + l15;
                if (m < NF) {
                    #pragma unroll
                    for (int r = 0; r < 4; ++r) {
                        const int n = nt * 16 + quad * 4 + r;
                        if (n < NF) {
                            // x = 2*log2e * (S + v1 + v2); S = sacc * 0.0625
                            float x = sacc[kk][it][r] * C1F
                                      + v1s2[kk * 36 + n] + v2s2[kk * 36 + m];
                            float e = exp2f(x);
                            const int idx = kk * NN2 + n * NF + m;
                            Ts[idx + (idx >> 3)] = 1.f - 2.f / (e + 1.f);
                        }
                    }
                }
            }
        }
    __syncthreads();
    // U-dot: logit u consumes T_flat[u*8 .. u*8+7] = Ts[9u .. 9u+7]
    #pragma unroll
    for (int u0 = 0; u0 < 2; ++u0) {
        const int u = t + u0 * 256;
        if (u < 324) {
            const float* tp = Ts + u * 9;
            float lg = Uws[8];
            #pragma unroll
            for (int j = 0; j < 8; ++j) lg += Uws[j] * tp[j];
            Ls[u] = lg;
        }
    }
    __syncthreads();
    // fused softmax: this block's 324 logits = rows [kp*9, kp*9+9) of out[b]
    #pragma unroll
    for (int rr0 = 0; rr0 < 3; ++rr0) {
        const int rr = wave + rr0 * 4;
        if (rr < 9) {
            float v = (lane < NF) ? Ls[rr * 36 + lane] : -INFINITY;
            float mx = v;
            #pragma unroll
            for (int off = 32; off > 0; off >>= 1) mx = fmaxf(mx, __shfl_xor(mx, off));
            float e = (lane < NF) ? __expf(v - mx) : 0.f;
            float sm = e;
            #pragma unroll
            for (int off = 32; off > 0; off >>= 1) sm += __shfl_xor(sm, off);
            if (lane < NF)
                out[(size_t)b * NN2 + kp * 324 + rr * 36 + lane] = e / sm;
        }
    }
}

extern "C" void kernel_launch(void* const* d_in, const int* in_sizes, int n_in,
                              void* d_out, int out_size, void* d_ws, size_t ws_size,
                              hipStream_t stream) {
    const float* texts = (const float*)d_in[0];
    const float* W     = (const float*)d_in[1];
    const float* Wb    = (const float*)d_in[2];
    const float* V1w   = (const float*)d_in[3];
    const float* V1b   = (const float*)d_in[4];
    const float* V2w   = (const float*)d_in[5];
    const float* V2b   = (const float*)d_in[6];
    const float* Uw    = (const float*)d_in[7];
    const float* Ub    = (const float*)d_in[8];

    char* ws = (char*)d_ws;
    f16x8* WfH = (f16x8*)ws;                                   //  1 MiB
    f16x8* XfH = (f16x8*)(ws + (1 << 20));                     // 24 MiB
    f16x8* XfL = (f16x8*)(ws + (1 << 20) + (size_t)NB * NFRAG * 16);       // 24 MiB
    float* v12 = (float*)(ws + (1 << 20) + (size_t)2 * NB * NFRAG * 16);   // 2.25 MiB
    float* outp = (float*)d_out;

    hipFuncSetAttribute((const void*)prep_all,
                        hipFuncAttributeMaxDynamicSharedMemorySize, SMEM_PREP);
    hipFuncSetAttribute((const void*)ntn_main,
                        hipFuncAttributeMaxDynamicSharedMemorySize, SMEM_MAIN);

    prep_all<<<128 + NB, 256, SMEM_PREP, stream>>>(W, WfH, texts, XfH, XfL,
                                                   V1w, V1b, V2w, V2b, Wb, v12);
    ntn_main<<<NB * NK / 2, 256, SMEM_MAIN, stream>>>(XfH, XfL, WfH, v12, Uw, Ub, outp);
}

// Round 9
// 186.486 us; speedup vs baseline: 1.1429x; 1.0699x over previous
//
#include <hip/hip_runtime.h>
#include <math.h>

#define NB 1024
#define NF 36
#define ED 256
#define NK 8
#define NN2 1296   // 36*36
#define QPK 162    // 1296/8

typedef _Float16 f16;
typedef f16 f16x4 __attribute__((ext_vector_type(4)));
typedef f16 f16x8 __attribute__((ext_vector_type(8)));
typedef float f32x4 __attribute__((ext_vector_type(4)));

#define WXSTR 136     // f16 per Wx half-row (128 + 8 pad); 272B = 17*16 (b128-aligned)
#define WXHSZ 13056   // 48 * WXSTR * 2 bytes
#define NFRAG 1536    // 3 row-tiles * 8 kc * 64 lanes, f16x8 each

// ---- ntn_main LDS: Xh | Wxh/Ts | v1 v2 Uw L  = 39540 B -> 4 blocks/CU ----
#define XH_OFF  0
#define WXH_OFF 24576
#define V_OFF   (24576 + WXHSZ)                  // 37632
#define SMEM_MAIN (V_OFF + (72 + 72 + 9 + 324) * 4)   // 39540; 4x = 158160 <= 163840

// ---- prep_all LDS: VfH | VfL | partials  = 28672 B -> 5 blocks/CU ----
#define PVH_OFF 0
#define PVL_OFF 8192
#define PP_OFF  16384
#define SMEM_PREP 28672

#define TWO_LOG2E 2.8853900817779268f
#define C1F (0.0625f * TWO_LOG2E)

__device__ __forceinline__ f32x4 mfma16(f16x8 a, f16x8 b, f32x4 c) {
    return __builtin_amdgcn_mfma_f32_16x16x32_f16(a, b, c, 0, 0, 0);
}

// blocks [0,128): W fragment pack, one (k,ct) tile per block.
// blocks [128,1152): X fragment pack (hi to global; lo kept in registers for
//   the v12 MFMA only — ntn no longer consumes X-lo at all).
// Wb is folded into the v2 row: v2'[k,m] = (V2w[k]+Wb[k]).x_m + V2b[k].
__global__ __launch_bounds__(256, 4) void prep_all(
    const float* __restrict__ W, f16x8* __restrict__ WfH,
    const float* __restrict__ texts, f16x8* __restrict__ XfH,
    const float* __restrict__ V1w, const float* __restrict__ V1b,
    const float* __restrict__ V2w, const float* __restrict__ V2b,
    const float* __restrict__ Wb, float* __restrict__ v12)
{
    extern __shared__ char psmem[];
    const int blk = blockIdx.x;
    const int t = threadIdx.x;
    const int wave = t >> 6, lane = t & 63;

    if (blk < 128) {   // ---- W pack: (k, ct) tile ----
        const int k = blk >> 4, ct = blk & 15;
        f16* Wl = (f16*)psmem;                    // [16][264] f16, scaled x16
        {
            const int r = t >> 4, seg = t & 15;   // row in tile, 16-float segment
            const float* src = W + ((size_t)(k * 256 + ct * 16 + r)) * 256 + seg * 16;
            f16* d = Wl + r * 264 + seg * 16;
            #pragma unroll
            for (int j4 = 0; j4 < 4; ++j4) {
                float4 a = ((const float4*)src)[j4];
                d[j4 * 4 + 0] = (f16)(a.x * 16.0f);
                d[j4 * 4 + 1] = (f16)(a.y * 16.0f);
                d[j4 * 4 + 2] = (f16)(a.z * 16.0f);
                d[j4 * 4 + 3] = (f16)(a.w * 16.0f);
            }
        }
        __syncthreads();
        f16x8* dst = WfH + (size_t)(k * 16 + ct) * 8 * 64;
        #pragma unroll
        for (int e0 = 0; e0 < 2; ++e0) {
            const int e = t + e0 * 256;           // [0,512) output entries
            const int kc = e >> 6, el = e & 63, qd = el >> 4, l15 = el & 15;
            dst[e] = *(const f16x8*)(Wl + l15 * 264 + (kc * 4 + qd) * 8);
        }
        return;
    }

    // ---- X fragment pack + v12 ----
    f16x8* VfH = (f16x8*)(psmem + PVH_OFF);
    f16x8* VfL = (f16x8*)(psmem + PVL_OFF);
    f32x4* Pp  = (f32x4*)(psmem + PP_OFF);        // [4 waves][3 rt][64 lanes]

    const int b = blk - 128;
    const float* xb = texts + (size_t)b * NF * ED;

    // V fragments: col = which*8 + k at lane&15; scaled by 16; Wb folded into V2
    #pragma unroll
    for (int i0 = 0; i0 < 2; ++i0) {
        int i = t + i0 * 256;          // [0,512)
        int kc = (i >> 6) & 7, ln = i & 63;
        int q = ln >> 4, col = ln & 15;
        int which = col >> 3, kk = col & 7;
        const float* src  = (which ? V2w : V1w) + kk * 256 + kc * 32 + q * 8;
        const float* srcb = Wb + kk * 256 + kc * 32 + q * 8;
        f16x8 hi, lo;
        #pragma unroll
        for (int j = 0; j < 8; ++j) {
            float sv = src[j] + (which ? srcb[j] : 0.f);
            sv *= 16.0f;
            f16 h = (f16)sv;
            hi[j] = h;
            lo[j] = (f16)(sv - (float)h);
        }
        VfH[i] = hi;
        VfL[i] = lo;
    }

    // X fragments: direct global gather -> registers + hi-only global store.
    f16x8 FH[6], FL[6];
    #pragma unroll
    for (int i0 = 0; i0 < 6; ++i0) {
        int i = t + i0 * 256;          // [0,1536)
        int rt = i >> 9, kc = (i >> 6) & 7;
        int q = lane >> 4, l15 = lane & 15;
        int row = rt * 16 + l15;
        f16x8 hi, lo;
        if (row < NF) {
            const float* s = xb + row * ED + kc * 32 + q * 8;
            float4 a = *(const float4*)s;
            float4 c = *(const float4*)(s + 4);
            float v[8] = {a.x, a.y, a.z, a.w, c.x, c.y, c.z, c.w};
            #pragma unroll
            for (int j = 0; j < 8; ++j) {
                f16 h = (f16)v[j];
                hi[j] = h;
                lo[j] = (f16)(v[j] - (float)h);
            }
        } else {
            #pragma unroll
            for (int j = 0; j < 8; ++j) { hi[j] = (f16)0.f; lo[j] = (f16)0.f; }
        }
        FH[i0] = hi;
        FL[i0] = lo;
        XfH[(size_t)b * NFRAG + i] = hi;
    }
    __syncthreads();   // VfH/VfL staged

    // per-wave kc-partials of v12 (kc = wave and wave+4), all 3 row-tiles
    f32x4 pacc[3];
    #pragma unroll
    for (int rt = 0; rt < 3; ++rt) pacc[rt] = (f32x4){0.f, 0.f, 0.f, 0.f};
    #pragma unroll
    for (int rt = 0; rt < 3; ++rt) {
        #pragma unroll
        for (int s = 0; s < 2; ++s) {
            const int i0 = rt * 2 + s;          // frag (rt, kc = wave + 4*s)
            const int kc = wave + 4 * s;
            f16x8 bh = VfH[kc * 64 + lane];
            f16x8 bl = VfL[kc * 64 + lane];
            pacc[rt] = mfma16(FH[i0], bh, pacc[rt]);
            pacc[rt] = mfma16(FH[i0], bl, pacc[rt]);
            pacc[rt] = mfma16(FL[i0], bh, pacc[rt]);
        }
    }
    #pragma unroll
    for (int rt = 0; rt < 3; ++rt)
        Pp[(wave * 3 + rt) * 64 + lane] = pacc[rt];
    __syncthreads();

    // reduce 4 wave-partials; wave rt (<3) owns row-tile rt
    if (wave < 3) {
        f32x4 acc = Pp[(0 * 3 + wave) * 64 + lane];
        #pragma unroll
        for (int w = 1; w < 4; ++w) acc += Pp[(w * 3 + wave) * 64 + lane];
        const int q = lane >> 4, l15 = lane & 15;
        const int which = l15 >> 3, kk = l15 & 7;
        const float bias = which ? V2b[kk] : V1b[kk];
        #pragma unroll
        for (int r = 0; r < 4; ++r) {
            const int n = wave * 16 + q * 4 + r;
            if (n < NF)
                v12[((size_t)b * 16 + l15) * NF + n] = acc[r] * 0.0625f + bias;
        }
    }
}

// k-pair merged main (Xh staged in LDS) + fused softmax.
// Precision budget (validated R6/R9): Wx = Xh*Wh only, S = Wxh*Xh only.
// Dropped terms (Xl*W*X and Wx*Xl, each ~2^-11 rel) are below / at the
// Wxh-f16 quantization error already present (sqrt(256)*5e-4 ~ 0.008 on S).
// Phase 1 uses SWAPPED MFMA operands (A/B frag layouts symmetric) so the
// accumulator is Wx^T: lane holds 4 consecutive cols of one row -> packed
// f16x4 ds_write_b64 stores.
// Wxh stays *16-scaled; 0.0625*2*log2e folded into the epilogue fma.
__global__ __launch_bounds__(256, 4) void ntn_main(
    const f16x8* __restrict__ XfHG,
    const f16x8* __restrict__ WfH,
    const float* __restrict__ v12,
    const float* __restrict__ Uw, const float* __restrict__ Ubp,
    float* __restrict__ out)
{
    extern __shared__ char smem[];
    f16x8* Xh   = (f16x8*)(smem + XH_OFF);
    f16*   Wxh  = (f16*)(smem + WXH_OFF);
    float* v1s2 = (float*)(smem + V_OFF);      // [2][36], pre-scaled by 2*log2e
    float* v2s2 = v1s2 + 72;                   // [2][36]
    float* Uws  = v1s2 + 144;                  // [9]
    float* Ls   = v1s2 + 153;                  // [324] logits

    // XCD swizzle: the 4 k-pair blocks of a given b share id&7 (same XCD)
    const int id  = blockIdx.x;
    const int xcd = id & 7;
    const int rem = id >> 3;
    const int kp  = rem & 3;
    const int b   = ((rem >> 2) << 3) | xcd;
    const int k0  = kp * 2;

    const int t    = threadIdx.x;
    const int wave = t >> 6;
    const int lane = t & 63;
    const int quad = lane >> 4;
    const int l15  = lane & 15;

    // ---- stage X-hi fragments into LDS (coalesced dwordx4) ----
    {
        const f16x8* gh = XfHG + (size_t)b * NFRAG;
        #pragma unroll
        for (int i = 0; i < 6; ++i) Xh[t + i * 256] = gh[t + i * 256];
    }
    if (t < 144) {
        const int r = t / 36, n = t - r * 36;
        const int which = r & 1, kq = r >> 1;
        float v = v12[((size_t)b * 16 + which * 8 + (k0 + kq)) * NF + n] * TWO_LOG2E;
        (which ? v2s2 : v1s2)[kq * 36 + n] = v;
    }
    if (t < 8) Uws[t] = Uw[t];
    if (t == 8) Uws[8] = Ubp[0];
    __syncthreads();

    const f16x8* Wk0 = WfH + (size_t)k0 * 8192;   // 16ct*8kc*64
    const f16x8* Wk1 = Wk0 + 8192;

    f32x4 sacc[2][3];
    #pragma unroll
    for (int kk = 0; kk < 2; ++kk)
        #pragma unroll
        for (int it = 0; it < 3; ++it) sacc[kk][it] = (f32x4){0.f, 0.f, 0.f, 0.f};

    for (int h = 0; h < 2; ++h) {
        // ===== phase 1: Wx^T[, half h] for BOTH k's; swapped operands =====
        // acc[rt][j2][kk][r] = Wx[n = rt*16 + l15][c = ct*16 + quad*4 + r]
        f32x4 acc[3][2][2];   // [rt][ctslot][kk]
        #pragma unroll
        for (int i = 0; i < 3; ++i)
            #pragma unroll
            for (int j = 0; j < 2; ++j) {
                acc[i][j][0] = (f32x4){0.f, 0.f, 0.f, 0.f};
                acc[i][j][1] = (f32x4){0.f, 0.f, 0.f, 0.f};
            }
        const int ct0 = h * 8 + wave;
        const int ct1 = ct0 + 4;
        #pragma unroll 2
        for (int kc = 0; kc < 8; ++kc) {
            f16x8 w00 = Wk0[(ct0 * 8 + kc) * 64 + lane];
            f16x8 w01 = Wk0[(ct1 * 8 + kc) * 64 + lane];
            f16x8 w10 = Wk1[(ct0 * 8 + kc) * 64 + lane];
            f16x8 w11 = Wk1[(ct1 * 8 + kc) * 64 + lane];
            #pragma unroll
            for (int rt = 0; rt < 3; ++rt) {
                f16x8 ah = Xh[(rt * 8 + kc) * 64 + lane];    // LDS ds_read_b128
                acc[rt][0][0] = mfma16(w00, ah, acc[rt][0][0]);
                acc[rt][1][0] = mfma16(w01, ah, acc[rt][1][0]);
                acc[rt][0][1] = mfma16(w10, ah, acc[rt][0][1]);
                acc[rt][1][1] = mfma16(w11, ah, acc[rt][1][1]);
            }
        }
        // ===== per-k sequential: packed f16x4 store -> phase 2 =====
        #pragma unroll
        for (int kk = 0; kk < 2; ++kk) {
            __syncthreads();   // previous Wxh readers done
            #pragma unroll
            for (int rt = 0; rt < 3; ++rt) {
                const int n = rt * 16 + l15;
                #pragma unroll
                for (int j2 = 0; j2 < 2; ++j2) {
                    const int cb = (j2 ? (wave + 4) : wave) * 16 + quad * 4;
                    f16x4 h4;
                    #pragma unroll
                    for (int r = 0; r < 4; ++r) h4[r] = (f16)(acc[rt][j2][kk][r]);
                    *(f16x4*)(Wxh + n * WXSTR + cb) = h4;   // ds_write_b64
                }
            }
            __syncthreads();
            // phase 2: S_kk += Wxh * Xh^T (9 tiles over 4 waves)
            #pragma unroll
            for (int it = 0; it < 3; ++it) {
                const int p = wave + it * 4;
                if (p < 9) {
                    const int nt = p / 3, mt = p % 3;
                    const f16* wxh_p = Wxh + (nt * 16 + l15) * WXSTR + quad * 8;
                    #pragma unroll
                    for (int kc2 = 0; kc2 < 4; ++kc2) {
                        f16x8 pah = *(const f16x8*)(wxh_p + kc2 * 32);
                        f16x8 pbh = Xh[(mt * 8 + h * 4 + kc2) * 64 + lane];
                        sacc[kk][it] = mfma16(pah, pbh, sacc[kk][it]);
                    }
                }
            }
        }
    }

    // ===== epilogue: T = tanh(S + v1 + v2) -> Ts (chunk-padded, overlays Wxh) =====
    __syncthreads();
    float* Ts = (float*)Wxh;   // padded: addr = idx + (idx>>3)
    #pragma unroll
    for (int kk = 0; kk < 2; ++kk)
        #pragma unroll
        for (int it = 0; it < 3; ++it) {
            const int p = wave + it * 4;
            if (p < 9) {
                const int nt = p / 3, mt = p % 3;
                const int m = mt * 16 + l15;
                if (m < NF) {
                    #pragma unroll
                    for (int r = 0; r < 4; ++r) {
                        const int n = nt * 16 + quad * 4 + r;
                        if (n < NF) {
                            // x = 2*log2e * (S + v1 + v2); S = sacc * 0.0625
                            float x = sacc[kk][it][r] * C1F
                                      + v1s2[kk * 36 + n] + v2s2[kk * 36 + m];
                            float e = exp2f(x);
                            const int idx = kk * NN2 + n * NF + m;
                            Ts[idx + (idx >> 3)] = 1.f - 2.f / (e + 1.f);
                        }
                    }
                }
            }
        }
    __syncthreads();
    // U-dot: logit u consumes T_flat[u*8 .. u*8+7] = Ts[9u .. 9u+7]
    #pragma unroll
    for (int u0 = 0; u0 < 2; ++u0) {
        const int u = t + u0 * 256;
        if (u < 324) {
            const float* tp = Ts + u * 9;
            float lg = Uws[8];
            #pragma unroll
            for (int j = 0; j < 8; ++j) lg += Uws[j] * tp[j];
            Ls[u] = lg;
        }
    }
    __syncthreads();
    // fused softmax: this block's 324 logits = rows [kp*9, kp*9+9) of out[b]
    #pragma unroll
    for (int rr0 = 0; rr0 < 3; ++rr0) {
        const int rr = wave + rr0 * 4;
        if (rr < 9) {
            float v = (lane < NF) ? Ls[rr * 36 + lane] : -INFINITY;
            float mx = v;
            #pragma unroll
            for (int off = 32; off > 0; off >>= 1) mx = fmaxf(mx, __shfl_xor(mx, off));
            float e = (lane < NF) ? __expf(v - mx) : 0.f;
            float sm = e;
            #pragma unroll
            for (int off = 32; off > 0; off >>= 1) sm += __shfl_xor(sm, off);
            if (lane < NF)
                out[(size_t)b * NN2 + kp * 324 + rr * 36 + lane] = e / sm;
        }
    }
}

extern "C" void kernel_launch(void* const* d_in, const int* in_sizes, int n_in,
                              void* d_out, int out_size, void* d_ws, size_t ws_size,
                              hipStream_t stream) {
    const float* texts = (const float*)d_in[0];
    const float* W     = (const float*)d_in[1];
    const float* Wb    = (const float*)d_in[2];
    const float* V1w   = (const float*)d_in[3];
    const float* V1b   = (const float*)d_in[4];
    const float* V2w   = (const float*)d_in[5];
    const float* V2b   = (const float*)d_in[6];
    const float* Uw    = (const float*)d_in[7];
    const float* Ub    = (const float*)d_in[8];

    char* ws = (char*)d_ws;
    f16x8* WfH = (f16x8*)ws;                                   //  1 MiB
    f16x8* XfH = (f16x8*)(ws + (1 << 20));                     // 24 MiB
    float* v12 = (float*)(ws + (1 << 20) + (size_t)NB * NFRAG * 16);   // 2.25 MiB
    float* outp = (float*)d_out;

    hipFuncSetAttribute((const void*)prep_all,
                        hipFuncAttributeMaxDynamicSharedMemorySize, SMEM_PREP);
    hipFuncSetAttribute((const void*)ntn_main,
                        hipFuncAttributeMaxDynamicSharedMemorySize, SMEM_MAIN);

    prep_all<<<128 + NB, 256, SMEM_PREP, stream>>>(W, WfH, texts, XfH,
                                                   V1w, V1b, V2w, V2b, Wb, v12);
    ntn_main<<<NB * NK / 2, 256, SMEM_MAIN, stream>>>(XfH, WfH, v12, Uw, Ub, outp);
}

// Round 10
// 181.960 us; speedup vs baseline: 1.1713x; 1.0249x over previous
//
#include <hip/hip_runtime.h>
#include <math.h>

#define NB 1024
#define NF 36
#define ED 256
#define NK 8
#define NN2 1296   // 36*36
#define QPK 162    // 1296/8

typedef _Float16 f16;
typedef f16 f16x4 __attribute__((ext_vector_type(4)));
typedef f16 f16x8 __attribute__((ext_vector_type(8)));
typedef float f32x4 __attribute__((ext_vector_type(4)));

#define WXSTR 136     // f16 per Wx half-row (128 + 8 pad); 272B = 17*16 (b128-aligned)
#define WXHSZ 13056   // 48 * WXSTR * 2 bytes
#define NFRAG 1536    // 3 row-tiles * 8 kc * 64 lanes, f16x8 each

// ---- ntn_main LDS: Xh | Wxh/Ts | v1 v2 Uw L  = 39540 B -> 4 blocks/CU ----
#define XH_OFF  0
#define WXH_OFF 24576
#define V_OFF   (24576 + WXHSZ)                  // 37632
#define SMEM_MAIN (V_OFF + (72 + 72 + 9 + 324) * 4)   // 39540; 4x = 158160 <= 163840

// ---- prep_all LDS: VfH | VfL | partials  = 28672 B -> 5 blocks/CU ----
#define PVH_OFF 0
#define PVL_OFF 8192
#define PP_OFF  16384
#define SMEM_PREP 28672

#define TWO_LOG2E 2.8853900817779268f
#define C1F (0.0625f * TWO_LOG2E)

__device__ __forceinline__ f32x4 mfma16(f16x8 a, f16x8 b, f32x4 c) {
    return __builtin_amdgcn_mfma_f32_16x16x32_f16(a, b, c, 0, 0, 0);
}

// blocks [0,128): W fragment pack, one (k,ct) tile per block.
// blocks [128,1152): X fragment pack (hi to global; lo kept in registers for
//   the v12 MFMA only — ntn no longer consumes X-lo at all).
// Wb is folded into the v2 row: v2'[k,m] = (V2w[k]+Wb[k]).x_m + V2b[k].
__global__ __launch_bounds__(256, 4) void prep_all(
    const float* __restrict__ W, f16x8* __restrict__ WfH,
    const float* __restrict__ texts, f16x8* __restrict__ XfH,
    const float* __restrict__ V1w, const float* __restrict__ V1b,
    const float* __restrict__ V2w, const float* __restrict__ V2b,
    const float* __restrict__ Wb, float* __restrict__ v12)
{
    extern __shared__ char psmem[];
    const int blk = blockIdx.x;
    const int t = threadIdx.x;
    const int wave = t >> 6, lane = t & 63;

    if (blk < 128) {   // ---- W pack: (k, ct) tile ----
        const int k = blk >> 4, ct = blk & 15;
        f16* Wl = (f16*)psmem;                    // [16][264] f16, scaled x16
        {
            const int r = t >> 4, seg = t & 15;   // row in tile, 16-float segment
            const float* src = W + ((size_t)(k * 256 + ct * 16 + r)) * 256 + seg * 16;
            f16* d = Wl + r * 264 + seg * 16;
            #pragma unroll
            for (int j4 = 0; j4 < 4; ++j4) {
                float4 a = ((const float4*)src)[j4];
                d[j4 * 4 + 0] = (f16)(a.x * 16.0f);
                d[j4 * 4 + 1] = (f16)(a.y * 16.0f);
                d[j4 * 4 + 2] = (f16)(a.z * 16.0f);
                d[j4 * 4 + 3] = (f16)(a.w * 16.0f);
            }
        }
        __syncthreads();
        f16x8* dst = WfH + (size_t)(k * 16 + ct) * 8 * 64;
        #pragma unroll
        for (int e0 = 0; e0 < 2; ++e0) {
            const int e = t + e0 * 256;           // [0,512) output entries
            const int kc = e >> 6, el = e & 63, qd = el >> 4, l15 = el & 15;
            dst[e] = *(const f16x8*)(Wl + l15 * 264 + (kc * 4 + qd) * 8);
        }
        return;
    }

    // ---- X fragment pack + v12 ----
    f16x8* VfH = (f16x8*)(psmem + PVH_OFF);
    f16x8* VfL = (f16x8*)(psmem + PVL_OFF);
    f32x4* Pp  = (f32x4*)(psmem + PP_OFF);        // [4 waves][3 rt][64 lanes]

    const int b = blk - 128;
    const float* xb = texts + (size_t)b * NF * ED;

    // V fragments: col = which*8 + k at lane&15; scaled by 16; Wb folded into V2
    #pragma unroll
    for (int i0 = 0; i0 < 2; ++i0) {
        int i = t + i0 * 256;          // [0,512)
        int kc = (i >> 6) & 7, ln = i & 63;
        int q = ln >> 4, col = ln & 15;
        int which = col >> 3, kk = col & 7;
        const float* src  = (which ? V2w : V1w) + kk * 256 + kc * 32 + q * 8;
        const float* srcb = Wb + kk * 256 + kc * 32 + q * 8;
        f16x8 hi, lo;
        #pragma unroll
        for (int j = 0; j < 8; ++j) {
            float sv = src[j] + (which ? srcb[j] : 0.f);
            sv *= 16.0f;
            f16 h = (f16)sv;
            hi[j] = h;
            lo[j] = (f16)(sv - (float)h);
        }
        VfH[i] = hi;
        VfL[i] = lo;
    }

    // X fragments: direct global gather -> registers + hi-only global store.
    f16x8 FH[6], FL[6];
    #pragma unroll
    for (int i0 = 0; i0 < 6; ++i0) {
        int i = t + i0 * 256;          // [0,1536)
        int rt = i >> 9, kc = (i >> 6) & 7;
        int q = lane >> 4, l15 = lane & 15;
        int row = rt * 16 + l15;
        f16x8 hi, lo;
        if (row < NF) {
            const float* s = xb + row * ED + kc * 32 + q * 8;
            float4 a = *(const float4*)s;
            float4 c = *(const float4*)(s + 4);
            float v[8] = {a.x, a.y, a.z, a.w, c.x, c.y, c.z, c.w};
            #pragma unroll
            for (int j = 0; j < 8; ++j) {
                f16 h = (f16)v[j];
                hi[j] = h;
                lo[j] = (f16)(v[j] - (float)h);
            }
        } else {
            #pragma unroll
            for (int j = 0; j < 8; ++j) { hi[j] = (f16)0.f; lo[j] = (f16)0.f; }
        }
        FH[i0] = hi;
        FL[i0] = lo;
        XfH[(size_t)b * NFRAG + i] = hi;
    }
    __syncthreads();   // VfH/VfL staged

    // per-wave kc-partials of v12 (kc = wave and wave+4), all 3 row-tiles
    f32x4 pacc[3];
    #pragma unroll
    for (int rt = 0; rt < 3; ++rt) pacc[rt] = (f32x4){0.f, 0.f, 0.f, 0.f};
    #pragma unroll
    for (int rt = 0; rt < 3; ++rt) {
        #pragma unroll
        for (int s = 0; s < 2; ++s) {
            const int i0 = rt * 2 + s;          // frag (rt, kc = wave + 4*s)
            const int kc = wave + 4 * s;
            f16x8 bh = VfH[kc * 64 + lane];
            f16x8 bl = VfL[kc * 64 + lane];
            pacc[rt] = mfma16(FH[i0], bh, pacc[rt]);
            pacc[rt] = mfma16(FH[i0], bl, pacc[rt]);
            pacc[rt] = mfma16(FL[i0], bh, pacc[rt]);
        }
    }
    #pragma unroll
    for (int rt = 0; rt < 3; ++rt)
        Pp[(wave * 3 + rt) * 64 + lane] = pacc[rt];
    __syncthreads();

    // reduce 4 wave-partials; wave rt (<3) owns row-tile rt
    if (wave < 3) {
        f32x4 acc = Pp[(0 * 3 + wave) * 64 + lane];
        #pragma unroll
        for (int w = 1; w < 4; ++w) acc += Pp[(w * 3 + wave) * 64 + lane];
        const int q = lane >> 4, l15 = lane & 15;
        const int which = l15 >> 3, kk = l15 & 7;
        const float bias = which ? V2b[kk] : V1b[kk];
        #pragma unroll
        for (int r = 0; r < 4; ++r) {
            const int n = wave * 16 + q * 4 + r;
            if (n < NF)
                v12[((size_t)b * 16 + l15) * NF + n] = acc[r] * 0.0625f + bias;
        }
    }
}

// ---- ntn_main building blocks ----
// P1 step: one kc of Wx^T = W*X (swapped operands) for ONE k, 6 MFMA.
#define P1_STEP(ACC, WKP, H, KC) do {                                         \
    f16x8 w0_ = (WKP)[((((H) * 8 + wave) * 8) + (KC)) * 64 + lane];           \
    f16x8 w1_ = (WKP)[((((H) * 8 + wave + 4) * 8) + (KC)) * 64 + lane];       \
    _Pragma("unroll")                                                         \
    for (int rt_ = 0; rt_ < 3; ++rt_) {                                       \
        f16x8 ah_ = Xh[(rt_ * 8 + (KC)) * 64 + lane];                         \
        ACC[rt_][0] = mfma16(w0_, ah_, ACC[rt_][0]);                          \
        ACC[rt_][1] = mfma16(w1_, ah_, ACC[rt_][1]);                          \
    }                                                                         \
} while (0)

// P2 tile IT for half H, k-slot KK: reads current Wxh contents.
#define P2_TILE(IT, H, KK) do {                                               \
    const int p_ = wave + (IT) * 4;                                           \
    if (p_ < 9) {                                                             \
        const int nt_ = p_ / 3, mt_ = p_ % 3;                                 \
        const f16* wp_ = Wxh + (nt_ * 16 + l15) * WXSTR + quad * 8;           \
        _Pragma("unroll")                                                     \
        for (int kc2_ = 0; kc2_ < 4; ++kc2_) {                                \
            f16x8 pah_ = *(const f16x8*)(wp_ + kc2_ * 32);                    \
            f16x8 pbh_ = Xh[(mt_ * 8 + (H) * 4 + kc2_) * 64 + lane];          \
            sacc[KK][IT] = mfma16(pah_, pbh_, sacc[KK][IT]);                  \
        }                                                                     \
    }                                                                         \
} while (0)

#define ZERO_ACC(ACC) do {                                                    \
    _Pragma("unroll")                                                         \
    for (int i_ = 0; i_ < 3; ++i_) {                                          \
        ACC[i_][0] = (f32x4){0.f, 0.f, 0.f, 0.f};                             \
        ACC[i_][1] = (f32x4){0.f, 0.f, 0.f, 0.f};                             \
    }                                                                         \
} while (0)

// packed f16x4 store of one k's Wx half (transposed acc: 4 consecutive cols)
#define STORE_WX(ACC) do {                                                    \
    _Pragma("unroll")                                                         \
    for (int rt_ = 0; rt_ < 3; ++rt_) {                                       \
        const int n_ = rt_ * 16 + l15;                                        \
        _Pragma("unroll")                                                     \
        for (int j2_ = 0; j2_ < 2; ++j2_) {                                   \
            const int cb_ = (j2_ ? (wave + 4) : wave) * 16 + quad * 4;        \
            f16x4 h4_;                                                        \
            _Pragma("unroll")                                                 \
            for (int r_ = 0; r_ < 4; ++r_) h4_[r_] = (f16)(ACC[rt_][j2_][r_]);\
            *(f16x4*)(Wxh + n_ * WXSTR + cb_) = h4_;                          \
        }                                                                     \
    }                                                                         \
} while (0)

// Fused segment: P1 of (H1, k via WKP) interleaved with P2 of (HP, KKP).
// Barrier-free region: P2 reads Wxh (prev store), P1 is reg/Xh/global only.
#define SEG_FUSED(ACC, WKP, H1, HP, KKP) do {                                 \
    _Pragma("unroll")                                                         \
    for (int kc_ = 0; kc_ < 8; ++kc_) {                                       \
        P1_STEP(ACC, WKP, H1, kc_);                                           \
        if (kc_ == 1) P2_TILE(0, HP, KKP);                                    \
        if (kc_ == 3) P2_TILE(1, HP, KKP);                                    \
        if (kc_ == 5) P2_TILE(2, HP, KKP);                                    \
    }                                                                         \
} while (0)

// k-pair merged main (Xh staged in LDS) + fused softmax.
// Precision budget (validated R6/R9): Wx = Xh*Wh only, S = Wxh*Xh only.
// Phase 1 per-k with swapped MFMA operands (acc = Wx^T -> packed b64 store).
// Pipeline: store(h0k0); [P2(h0k0) || P1(h0k1)]; store; [P2(h0k1) || P1(h1k0)];
// store; [P2(h1k0) || P1(h1k1)]; store; P2(h1k1) tail. Same 8 in-loop barriers
// as R9 but 3 of 4 pre-store barriers now end 60-MFMA regions (was 12).
__global__ __launch_bounds__(256, 4) void ntn_main(
    const f16x8* __restrict__ XfHG,
    const f16x8* __restrict__ WfH,
    const float* __restrict__ v12,
    const float* __restrict__ Uw, const float* __restrict__ Ubp,
    float* __restrict__ out)
{
    extern __shared__ char smem[];
    f16x8* Xh   = (f16x8*)(smem + XH_OFF);
    f16*   Wxh  = (f16*)(smem + WXH_OFF);
    float* v1s2 = (float*)(smem + V_OFF);      // [2][36], pre-scaled by 2*log2e
    float* v2s2 = v1s2 + 72;                   // [2][36]
    float* Uws  = v1s2 + 144;                  // [9]
    float* Ls   = v1s2 + 153;                  // [324] logits

    // XCD swizzle: the 4 k-pair blocks of a given b share id&7 (same XCD)
    const int id  = blockIdx.x;
    const int xcd = id & 7;
    const int rem = id >> 3;
    const int kp  = rem & 3;
    const int b   = ((rem >> 2) << 3) | xcd;
    const int k0  = kp * 2;

    const int t    = threadIdx.x;
    const int wave = t >> 6;
    const int lane = t & 63;
    const int quad = lane >> 4;
    const int l15  = lane & 15;

    // ---- stage X-hi fragments into LDS (coalesced dwordx4) ----
    {
        const f16x8* gh = XfHG + (size_t)b * NFRAG;
        #pragma unroll
        for (int i = 0; i < 6; ++i) Xh[t + i * 256] = gh[t + i * 256];
    }
    if (t < 144) {
        const int r = t / 36, n = t - r * 36;
        const int which = r & 1, kq = r >> 1;
        float v = v12[((size_t)b * 16 + which * 8 + (k0 + kq)) * NF + n] * TWO_LOG2E;
        (which ? v2s2 : v1s2)[kq * 36 + n] = v;
    }
    if (t < 8) Uws[t] = Uw[t];
    if (t == 8) Uws[8] = Ubp[0];
    __syncthreads();

    const f16x8* Wk0 = WfH + (size_t)k0 * 8192;   // 16ct*8kc*64
    const f16x8* Wk1 = Wk0 + 8192;

    f32x4 sacc[2][3];
    #pragma unroll
    for (int kk = 0; kk < 2; ++kk)
        #pragma unroll
        for (int it = 0; it < 3; ++it) sacc[kk][it] = (f32x4){0.f, 0.f, 0.f, 0.f};

    f32x4 acc[3][2];

    // ===== seg 0: P1(h0,k0) alone =====
    ZERO_ACC(acc);
    #pragma unroll
    for (int kc = 0; kc < 8; ++kc) P1_STEP(acc, Wk0, 0, kc);
    STORE_WX(acc);               // Wxh unread so far: no pre-store barrier
    __syncthreads();             // (1) Wx(h0,k0) visible

    // ===== seg 1: P2(h0,k0) || P1(h0,k1) =====
    ZERO_ACC(acc);
    SEG_FUSED(acc, Wk1, 0, 0, 0);
    __syncthreads();             // (2) P2 reads done
    STORE_WX(acc);
    __syncthreads();             // (3) Wx(h0,k1) visible

    // ===== seg 2: P2(h0,k1) || P1(h1,k0) =====
    ZERO_ACC(acc);
    SEG_FUSED(acc, Wk0, 1, 0, 1);
    __syncthreads();             // (4)
    STORE_WX(acc);
    __syncthreads();             // (5) Wx(h1,k0) visible

    // ===== seg 3: P2(h1,k0) || P1(h1,k1) =====
    ZERO_ACC(acc);
    SEG_FUSED(acc, Wk1, 1, 1, 0);
    __syncthreads();             // (6)
    STORE_WX(acc);
    __syncthreads();             // (7) Wx(h1,k1) visible

    // ===== tail: P2(h1,k1) =====
    P2_TILE(0, 1, 1);
    P2_TILE(1, 1, 1);
    P2_TILE(2, 1, 1);

    // ===== epilogue: T = tanh(S + v1 + v2) -> Ts (chunk-padded, overlays Wxh) =====
    __syncthreads();             // (8) Wxh reads done before Ts overlay
    float* Ts = (float*)Wxh;     // padded: addr = idx + (idx>>3)
    #pragma unroll
    for (int kk = 0; kk < 2; ++kk)
        #pragma unroll
        for (int it = 0; it < 3; ++it) {
            const int p = wave + it * 4;
            if (p < 9) {
                const int nt = p / 3, mt = p % 3;
                const int m = mt * 16 + l15;
                if (m < NF) {
                    #pragma unroll
                    for (int r = 0; r < 4; ++r) {
                        const int n = nt * 16 + quad * 4 + r;
                        if (n < NF) {
                            // x = 2*log2e * (S + v1 + v2); S = sacc * 0.0625
                            float x = sacc[kk][it][r] * C1F
                                      + v1s2[kk * 36 + n] + v2s2[kk * 36 + m];
                            float e = exp2f(x);
                            const int idx = kk * NN2 + n * NF + m;
                            Ts[idx + (idx >> 3)] = 1.f - 2.f / (e + 1.f);
                        }
                    }
                }
            }
        }
    __syncthreads();
    // U-dot: logit u consumes T_flat[u*8 .. u*8+7] = Ts[9u .. 9u+7]
    #pragma unroll
    for (int u0 = 0; u0 < 2; ++u0) {
        const int u = t + u0 * 256;
        if (u < 324) {
            const float* tp = Ts + u * 9;
            float lg = Uws[8];
            #pragma unroll
            for (int j = 0; j < 8; ++j) lg += Uws[j] * tp[j];
            Ls[u] = lg;
        }
    }
    __syncthreads();
    // fused softmax: this block's 324 logits = rows [kp*9, kp*9+9) of out[b]
    #pragma unroll
    for (int rr0 = 0; rr0 < 3; ++rr0) {
        const int rr = wave + rr0 * 4;
        if (rr < 9) {
            float v = (lane < NF) ? Ls[rr * 36 + lane] : -INFINITY;
            float mx = v;
            #pragma unroll
            for (int off = 32; off > 0; off >>= 1) mx = fmaxf(mx, __shfl_xor(mx, off));
            float e = (lane < NF) ? __expf(v - mx) : 0.f;
            float sm = e;
            #pragma unroll
            for (int off = 32; off > 0; off >>= 1) sm += __shfl_xor(sm, off);
            if (lane < NF)
                out[(size_t)b * NN2 + kp * 324 + rr * 36 + lane] = e / sm;
        }
    }
}

extern "C" void kernel_launch(void* const* d_in, const int* in_sizes, int n_in,
                              void* d_out, int out_size, void* d_ws, size_t ws_size,
                              hipStream_t stream) {
    const float* texts = (const float*)d_in[0];
    const float* W     = (const float*)d_in[1];
    const float* Wb    = (const float*)d_in[2];
    const float* V1w   = (const float*)d_in[3];
    const float* V1b   = (const float*)d_in[4];
    const float* V2w   = (const float*)d_in[5];
    const float* V2b   = (const float*)d_in[6];
    const float* Uw    = (const float*)d_in[7];
    const float* Ub    = (const float*)d_in[8];

    char* ws = (char*)d_ws;
    f16x8* WfH = (f16x8*)ws;                                   //  1 MiB
    f16x8* XfH = (f16x8*)(ws + (1 << 20));                     // 24 MiB
    float* v12 = (float*)(ws + (1 << 20) + (size_t)NB * NFRAG * 16);   // 2.25 MiB
    float* outp = (float*)d_out;

    hipFuncSetAttribute((const void*)prep_all,
                        hipFuncAttributeMaxDynamicSharedMemorySize, SMEM_PREP);
    hipFuncSetAttribute((const void*)ntn_main,
                        hipFuncAttributeMaxDynamicSharedMemorySize, SMEM_MAIN);

    prep_all<<<128 + NB, 256, SMEM_PREP, stream>>>(W, WfH, texts, XfH,
                                                   V1w, V1b, V2w, V2b, Wb, v12);
    ntn_main<<<NB * NK / 2, 256, SMEM_MAIN, stream>>>(XfH, WfH, v12, Uw, Ub, outp);
}